// Round 9
// baseline (713.576 us; speedup 1.0000x reference)
//
#include <hip/hip_runtime.h>

typedef __attribute__((ext_vector_type(8))) short short8;
typedef __attribute__((ext_vector_type(16))) float f32x16;
typedef __attribute__((ext_vector_type(4))) unsigned short u16x4;
typedef unsigned short u16;

#define D_DIM 1024
#define NKT 64  // K / 16

__device__ __forceinline__ u16 f2bf(float f) {
  unsigned u = __builtin_bit_cast(unsigned, f);
  u += 0x7fffu + ((u >> 16) & 1u);
  return (u16)(u >> 16);
}
__device__ __forceinline__ float bf2f(u16 b) {
  return __builtin_bit_cast(float, ((unsigned)b) << 16);
}
__device__ __forceinline__ float gelu_f(float x) {
  float i = 0.7978845608028654f * (x + 0.044715f * x * x * x);
  float ex = __builtin_amdgcn_exp2f(i * 2.885390081777927f);  // e^{2i}
  float th = 1.0f - 2.0f * __builtin_amdgcn_rcpf(ex + 1.0f);
  return 0.5f * x * (1.0f + th);
}
__device__ __forceinline__ f32x16 mfma32(short8 a, short8 b, f32x16 c) {
  return __builtin_amdgcn_mfma_f32_32x32x16_bf16(a, b, c, 0, 0, 0);
}
__device__ __forceinline__ void glds16(const u16* g, const u16* l) {
  __builtin_amdgcn_global_load_lds(
      (const __attribute__((address_space(1))) void*)g,
      (__attribute__((address_space(3))) void*)l, 16, 0, 0);
}

// ---------------- prep kernels ----------------
__global__ __launch_bounds__(256) void prep_w_kernel(
    const float* __restrict__ W, u16* __restrict__ Wth, u16* __restrict__ Wtl) {
  __shared__ float tile[64][65];
  const int t = threadIdx.x;
  const int k0 = blockIdx.x * 64, n0 = blockIdx.y * 64;
  const size_t lbase = (size_t)blockIdx.z * D_DIM * D_DIM;
#pragma unroll
  for (int j = 0; j < 16; ++j) {
    int idx = t + 256 * j;
    int r = idx >> 6, c = idx & 63;
    tile[r][c] = W[lbase + (size_t)(k0 + r) * D_DIM + (n0 + c)];
  }
  __syncthreads();
#pragma unroll
  for (int j = 0; j < 16; ++j) {
    int idx = t + 256 * j;
    int r = idx >> 6, c = idx & 63;
    float f = tile[c][r];
    u16 hb = f2bf(f);
    u16 lb = f2bf(f - bf2f(hb));
    size_t oidx = lbase + (size_t)(n0 + r) * D_DIM + (k0 + c);
    Wth[oidx] = hb;
    Wtl[oidx] = lb;
  }
}

__global__ __launch_bounds__(256) void prep_x_kernel(
    const float* __restrict__ x, u16* __restrict__ xh, u16* __restrict__ xl) {
  size_t i = ((size_t)blockIdx.x * 256 + threadIdx.x) * 4;
  const float4 v = *(const float4*)(x + i);
  const float fv[4] = {v.x, v.y, v.z, v.w};
  u16x4 h4, l4;
#pragma unroll
  for (int c = 0; c < 4; ++c) {
    u16 hb = f2bf(fv[c]);
    h4[c] = hb;
    l4[c] = f2bf(fv[c] - bf2f(hb));
  }
  *(u16x4*)(xh + i) = h4;
  *(u16x4*)(xl + i) = l4;
}

// ---------------- 256x128 GEMM (32x32x16 MFMA, 2 blocks/CU) + ACT ----------
// LDS buffer (12288 u16 = 24 KB): Ah[256][16] | Al | Bh[128][16] | Bl.
// 16B slot s of row r holds k-chunk s ^ (r&1)  (bank-balanced, coalesced src).
// One vmcnt(0)+barrier per tile; inter-block overlap (2 blocks/CU) fills
// stalls (m97 mechanism) instead of intra-block phasing.
__global__ __launch_bounds__(512, 4) void gemm_act_kernel(
    const u16* __restrict__ Ahp, const u16* __restrict__ Alp,
    const u16* __restrict__ Bhp, const u16* __restrict__ Blp,
    const float* __restrict__ bias, const float* __restrict__ halt_w,
    u16* __restrict__ Hh, u16* __restrict__ Hl, float* __restrict__ zpart,
    int M, int writeLo) {
  extern __shared__ u16 lds[];  // 64 KB declared; K-loop uses 48 KB
  const int t = threadIdx.x;
  const int bid = blockIdx.x;                  // 512 blocks
  const int wg = (bid & 7) * 64 + (bid >> 3);  // XCD-chunked, bijective
  const int bm0 = (wg >> 3) * 256;
  const int bn0 = (wg & 7) * 128;
  const int lane = t & 63, wid = t >> 6;
  const int wr = wid >> 1, wc = wid & 1;  // wave tile 64x64 at (wr*64, wc*64)
  const int l31 = lane & 31, hi = lane >> 5;

  // ---- staging: wave w stages A-hi rows 32w..+31 (1 glds), A-lo same,
  // and one of the four 32-row B quarters (waves 0-3: Bh, 4-7: Bl).
  const int srow = lane >> 1;                  // 0..31 within 32-row unit
  const int schunk = (lane & 1) ^ (srow & 1);  // slot l&1 holds this chunk
  const u16* aSh = Ahp + (size_t)(bm0 + 32 * wid + srow) * D_DIM + schunk * 8;
  const u16* aSl = Alp + (size_t)(bm0 + 32 * wid + srow) * D_DIM + schunk * 8;
  const int bw = wid & 3;
  const u16* bS = ((wid >> 2) ? Blp : Bhp) +
                  (size_t)(bn0 + 32 * bw + srow) * D_DIM + schunk * 8;
  const int a_dst = wid * 512 + lane * 8;
  const int b_dst = 8192 + (wid >> 2) * 2048 + bw * 512 + lane * 8;

  // ---- fragment read offsets (u16). A-frag for 32x32x16: row = l&31,
  // k-chunk = l>>5; slot = chunk ^ (row&1) = (l>>5) ^ (l&1).
  const int fslot = ((lane >> 5) ^ lane) & 1;
  int a_rd[2], b_rd[2];
#pragma unroll
  for (int m = 0; m < 2; ++m)
    a_rd[m] = (wr * 64 + m * 32 + l31) * 16 + fslot * 8;
#pragma unroll
  for (int n = 0; n < 2; ++n)
    b_rd[n] = 8192 + (wc * 64 + n * 32 + l31) * 16 + fslot * 8;

  f32x16 acc[2][2];
#pragma unroll
  for (int m = 0; m < 2; ++m)
#pragma unroll
    for (int n = 0; n < 2; ++n) acc[m][n] = (f32x16)0.0f;

  // prologue: stage tile 0 into buf 0
  glds16(aSh, lds + a_dst);
  glds16(aSl, lds + 4096 + a_dst);
  glds16(bS, lds + b_dst);

#pragma unroll 1
  for (int kt = 0; kt < NKT; ++kt) {
    asm volatile("s_waitcnt vmcnt(0)" ::: "memory");
    __builtin_amdgcn_s_barrier();
    asm volatile("" ::: "memory");
    const u16* Lb = lds + (kt & 1) * 12288;
    if (kt + 1 < NKT) {
      const int k0 = (kt + 1) << 4;
      u16* db = lds + (((kt + 1) & 1) ? 12288 : 0);
      glds16(aSh + k0, db + a_dst);
      glds16(aSl + k0, db + 4096 + a_dst);
      glds16(bS + k0, db + b_dst);
    }
    short8 ah[2], al[2], bh[2], bl[2];
#pragma unroll
    for (int m = 0; m < 2; ++m) {
      ah[m] = *(const short8*)(Lb + a_rd[m]);
      al[m] = *(const short8*)(Lb + 4096 + a_rd[m]);
    }
#pragma unroll
    for (int n = 0; n < 2; ++n) {
      bh[n] = *(const short8*)(Lb + b_rd[n]);
      bl[n] = *(const short8*)(Lb + 2048 + b_rd[n]);
    }
    __builtin_amdgcn_s_setprio(1);
#pragma unroll
    for (int m = 0; m < 2; ++m)
#pragma unroll
      for (int n = 0; n < 2; ++n)
        acc[m][n] = mfma32(ah[m], bh[n], acc[m][n]);
#pragma unroll
    for (int m = 0; m < 2; ++m)
#pragma unroll
      for (int n = 0; n < 2; ++n)
        acc[m][n] = mfma32(ah[m], bl[n], acc[m][n]);
#pragma unroll
    for (int m = 0; m < 2; ++m)
#pragma unroll
      for (int n = 0; n < 2; ++n)
        acc[m][n] = mfma32(al[m], bh[n], acc[m][n]);
    __builtin_amdgcn_s_setprio(0);
  }

  __syncthreads();  // K-loop retired; LDS free for epilogue

  // ---- epilogue: bias + gelu in place; halt partial dot
  // C/D (32x32): col = l&31, row = (reg&3) + 8*(reg>>2) + 4*(l>>5)
  float bv[2], hwv[2];
#pragma unroll
  for (int n = 0; n < 2; ++n) {
    int col = bn0 + wc * 64 + n * 32 + l31;
    bv[n] = bias[col];
    hwv[n] = halt_w[col];
  }
  float zp[2][16];
#pragma unroll
  for (int m = 0; m < 2; ++m)
#pragma unroll
    for (int r = 0; r < 16; ++r) {
      float z = 0.0f;
#pragma unroll
      for (int n = 0; n < 2; ++n) {
        float v = gelu_f(acc[m][n][r] + bv[n]);
        acc[m][n][r] = v;
        z += v * hwv[n];
      }
      zp[m][r] = z;
    }
#pragma unroll
  for (int off = 1; off < 32; off <<= 1)
#pragma unroll
    for (int m = 0; m < 2; ++m)
#pragma unroll
      for (int r = 0; r < 16; ++r) zp[m][r] += __shfl_xor(zp[m][r], off);
  float* zf = (float*)lds;  // [2][256]
  if (l31 == 0) {
#pragma unroll
    for (int m = 0; m < 2; ++m)
#pragma unroll
      for (int r = 0; r < 16; ++r) {
        int row = wr * 64 + m * 32 + (r & 3) + 8 * (r >> 2) + 4 * hi;
        zf[wc * 256 + row] = zp[m][r];
      }
  }
  __syncthreads();
  if (t < 256) zpart[(size_t)(wg & 7) * M + bm0 + t] = zf[t] + zf[256 + t];
  __syncthreads();

  // ---- hi plane repack + store (hp = u16[256][128] = 64 KB)
  u16* hp = lds;
#pragma unroll
  for (int m = 0; m < 2; ++m)
#pragma unroll
    for (int n = 0; n < 2; ++n)
#pragma unroll
      for (int r = 0; r < 16; ++r) {
        int row = wr * 64 + m * 32 + (r & 3) + 8 * (r >> 2) + 4 * hi;
        hp[row * 128 + wc * 64 + n * 32 + l31] = f2bf(acc[m][n][r]);
      }
  __syncthreads();
#pragma unroll
  for (int p = 0; p < 8; ++p) {
    int idx = p * 512 + t;
    int r = idx >> 4, c = idx & 15;
    *(short8*)(Hh + (size_t)(bm0 + r) * D_DIM + bn0 + c * 8) =
        *(const short8*)&hp[r * 128 + c * 8];
  }
  if (writeLo) {
    __syncthreads();
#pragma unroll
    for (int m = 0; m < 2; ++m)
#pragma unroll
      for (int n = 0; n < 2; ++n)
#pragma unroll
        for (int r = 0; r < 16; ++r) {
          int row = wr * 64 + m * 32 + (r & 3) + 8 * (r >> 2) + 4 * hi;
          float v = acc[m][n][r];
          hp[row * 128 + wc * 64 + n * 32 + l31] = f2bf(v - bf2f(f2bf(v)));
        }
    __syncthreads();
#pragma unroll
    for (int p = 0; p < 8; ++p) {
      int idx = p * 512 + t;
      int r = idx >> 4, c = idx & 15;
      *(short8*)(Hl + (size_t)(bm0 + r) * D_DIM + bn0 + c * 8) =
          *(const short8*)&hp[r * 128 + c * 8];
    }
  }
}

// ---------------- ACT scalar kernels ----------------
__global__ __launch_bounds__(256) void act_weights_kernel(
    const float* __restrict__ zpart, const float* __restrict__ halt_b,
    float* __restrict__ cum, float* __restrict__ rem, float* __restrict__ pond,
    float* __restrict__ wout, int step, int last, int M, int nblk) {
  int tok = blockIdx.x * 256 + threadIdx.x;
  float z = halt_b[0];
  for (int nb = 0; nb < nblk; ++nb) z += zpart[(size_t)nb * M + tok];
  float p = 1.0f / (1.0f + expf(-z));
  float c, r, q;
  if (step == 0) {
    c = 0.0f; r = 1.0f; q = 0.0f;
  } else {
    c = cum[tok]; r = rem[tok]; q = pond[tok];
  }
  float weight = last ? r : (((c + p) >= 0.99f) ? r : p);
  q += weight;
  c += weight;
  r = fmaxf(1.0f - c, 0.0f);
  cum[tok] = c;
  rem[tok] = r;
  pond[tok] = q;
  wout[tok] = weight;
}

// out (+)= sum_s w_s * h_s   (hi plane only)
__global__ __launch_bounds__(256) void act_out_kernel(
    const u16* __restrict__ hbase, size_t pstride, const float* __restrict__ w,
    int nsteps, int accum, float* __restrict__ out, int M) {
  size_t gid = (size_t)blockIdx.x * 256 + threadIdx.x;
  int tok = (int)(gid >> 7);
  int off = ((int)gid & 127) * 8;
  size_t base = (size_t)tok * D_DIM + off;
  float o[8];
  if (accum) {
    float4 a = *(const float4*)(out + base);
    float4 b = *(const float4*)(out + base + 4);
    o[0] = a.x; o[1] = a.y; o[2] = a.z; o[3] = a.w;
    o[4] = b.x; o[5] = b.y; o[6] = b.z; o[7] = b.w;
  } else {
#pragma unroll
    for (int j = 0; j < 8; ++j) o[j] = 0.0f;
  }
  for (int s = 0; s < nsteps; ++s) {
    float ws = w[(size_t)s * M + tok];
    short8 hi = *(const short8*)(hbase + (size_t)s * pstride + base);
#pragma unroll
    for (int j = 0; j < 8; ++j) o[j] += ws * bf2f((u16)hi[j]);
  }
  *(float4*)(out + base) = make_float4(o[0], o[1], o[2], o[3]);
  *(float4*)(out + base + 4) = make_float4(o[4], o[5], o[6], o[7]);
}

__global__ __launch_bounds__(256) void ponder_reduce_kernel(
    const float* __restrict__ pond, float* __restrict__ o, int n) {
  __shared__ float sh[256];
  float a = 0.0f;
  for (int i = threadIdx.x; i < n; i += 256) a += pond[i];
  sh[threadIdx.x] = a;
  __syncthreads();
  for (int s = 128; s; s >>= 1) {
    if ((int)threadIdx.x < s) sh[threadIdx.x] += sh[threadIdx.x + s];
    __syncthreads();
  }
  if (threadIdx.x == 0) o[0] = sh[0] / (float)n;
}

extern "C" void kernel_launch(void* const* d_in, const int* in_sizes, int n_in,
                              void* d_out, int out_size, void* d_ws,
                              size_t ws_size, hipStream_t stream) {
  const float* x = (const float*)d_in[0];
  const float* layer_w = (const float*)d_in[1];
  const float* layer_b = (const float*)d_in[2];
  const float* halt_w = (const float*)d_in[3];
  const float* halt_b = (const float*)d_in[4];
  float* out = (float*)d_out;

  const int D = D_DIM;
  const int M = in_sizes[0] / D;        // 16384
  const int L = in_sizes[1] / (D * D);  // 4
  const size_t MD = (size_t)M * D, DD = (size_t)D * D;

  char* ws = (char*)d_ws;
  size_t off = 0;
  auto alloc = [&](size_t bytes) {
    void* p = ws + off;
    off += (bytes + 255) & ~(size_t)255;
    return p;
  };
  u16* Wsplit = (u16*)alloc((size_t)L * 2 * DD * sizeof(u16));  // hi | lo
  float* zpart = (float*)alloc(8 * (size_t)M * 4);
  float* wbuf = (float*)alloc((size_t)L * M * 4);
  float* cum = (float*)alloc((size_t)M * 4);
  float* rem = (float*)alloc((size_t)M * 4);
  float* pond = (float*)alloc((size_t)M * 4);

  const size_t planeElems = 2 * MD;          // hi + lo (u16)
  const size_t planeBytes = planeElems * 2;  // 67.1 MB
  const bool deferred = (off + (size_t)(L + 1) * planeBytes) <= ws_size;
  const int nbufs = deferred ? (L + 1) : 2;
  u16* planes = (u16*)alloc((size_t)nbufs * planeBytes);

  hipFuncSetAttribute((const void*)gemm_act_kernel,
                      hipFuncAttributeMaxDynamicSharedMemorySize, 65536);

  prep_x_kernel<<<(unsigned)(MD / 1024), 256, 0, stream>>>(x, planes,
                                                           planes + MD);
  prep_w_kernel<<<dim3(D / 64, D / 64, L), 256, 0, stream>>>(
      layer_w, Wsplit, Wsplit + (size_t)L * DD);

  for (int s = 0; s < L; ++s) {
    u16* pin = planes + (size_t)(deferred ? s : (s & 1)) * planeElems;
    u16* pout =
        planes + (size_t)(deferred ? (s + 1) : ((s + 1) & 1)) * planeElems;
    gemm_act_kernel<<<dim3(M / 256 * (D / 128)), 512, 65536, stream>>>(
        pin, pin + MD, Wsplit + (size_t)s * DD, Wsplit + (size_t)(L + s) * DD,
        layer_b + (size_t)s * D, halt_w, pout, pout + MD, zpart, M,
        (s < L - 1) ? 1 : 0);
    act_weights_kernel<<<M / 256, 256, 0, stream>>>(
        zpart, halt_b, cum, rem, pond, wbuf + (size_t)s * M, s,
        (s == L - 1) ? 1 : 0, M, D / 128);
    if (!deferred)
      act_out_kernel<<<(unsigned)(MD / 2048), 256, 0, stream>>>(
          pout, 0, wbuf + (size_t)s * M, 1, (s > 0) ? 1 : 0, out, M);
  }
  if (deferred)
    act_out_kernel<<<(unsigned)(MD / 2048), 256, 0, stream>>>(
        planes + planeElems, planeElems, wbuf, L, 0, out, M);
  ponder_reduce_kernel<<<1, 256, 0, stream>>>(pond, out + MD, M);
}

// Round 10
// 548.882 us; speedup vs baseline: 1.3001x; 1.3001x over previous
//
#include <hip/hip_runtime.h>

typedef __attribute__((ext_vector_type(8))) short short8;
typedef __attribute__((ext_vector_type(4))) float f32x4;
typedef __attribute__((ext_vector_type(4))) unsigned short u16x4;
typedef unsigned short u16;

#define D_DIM 1024
#define NKT 32  // K / 32

__device__ __forceinline__ u16 f2bf(float f) {
  unsigned u = __builtin_bit_cast(unsigned, f);
  u += 0x7fffu + ((u >> 16) & 1u);
  return (u16)(u >> 16);
}
__device__ __forceinline__ float bf2f(u16 b) {
  return __builtin_bit_cast(float, ((unsigned)b) << 16);
}
__device__ __forceinline__ float gelu_f(float x) {
  float i = 0.7978845608028654f * (x + 0.044715f * x * x * x);
  float ex = __builtin_amdgcn_exp2f(i * 2.885390081777927f);  // e^{2i}
  float th = 1.0f - 2.0f * __builtin_amdgcn_rcpf(ex + 1.0f);
  return 0.5f * x * (1.0f + th);
}
__device__ __forceinline__ f32x4 mfma16(short8 a, short8 b, f32x4 c) {
  return __builtin_amdgcn_mfma_f32_16x16x32_bf16(a, b, c, 0, 0, 0);
}
__device__ __forceinline__ void glds16(const u16* g, const u16* l) {
  __builtin_amdgcn_global_load_lds(
      (const __attribute__((address_space(1))) void*)g,
      (__attribute__((address_space(3))) void*)l, 16, 0, 0);
}

// ---------------- prep kernels ----------------
__global__ __launch_bounds__(256) void prep_w_kernel(
    const float* __restrict__ W, u16* __restrict__ Wth, u16* __restrict__ Wtl) {
  __shared__ float tile[64][65];
  const int t = threadIdx.x;
  const int k0 = blockIdx.x * 64, n0 = blockIdx.y * 64;
  const size_t lbase = (size_t)blockIdx.z * D_DIM * D_DIM;
#pragma unroll
  for (int j = 0; j < 16; ++j) {
    int idx = t + 256 * j;
    int r = idx >> 6, c = idx & 63;
    tile[r][c] = W[lbase + (size_t)(k0 + r) * D_DIM + (n0 + c)];
  }
  __syncthreads();
#pragma unroll
  for (int j = 0; j < 16; ++j) {
    int idx = t + 256 * j;
    int r = idx >> 6, c = idx & 63;
    float f = tile[c][r];
    u16 hb = f2bf(f);
    u16 lb = f2bf(f - bf2f(hb));
    size_t oidx = lbase + (size_t)(n0 + r) * D_DIM + (k0 + c);
    Wth[oidx] = hb;
    Wtl[oidx] = lb;
  }
}

__global__ __launch_bounds__(256) void prep_x_kernel(
    const float* __restrict__ x, u16* __restrict__ xh, u16* __restrict__ xl,
    int* __restrict__ counts, int M) {
  if (blockIdx.x == 0 && threadIdx.x == 0) {
    counts[0] = M;  // exact count, layer 0
    counts[1] = M;  // padded count, layer 0
  }
  size_t i = ((size_t)blockIdx.x * 256 + threadIdx.x) * 4;
  const float4 v = *(const float4*)(x + i);
  const float fv[4] = {v.x, v.y, v.z, v.w};
  u16x4 h4, l4;
#pragma unroll
  for (int c = 0; c < 4; ++c) {
    u16 hb = f2bf(fv[c]);
    h4[c] = hb;
    l4[c] = f2bf(fv[c] - bf2f(hb));
  }
  *(u16x4*)(xh + i) = h4;
  *(u16x4*)(xl + i) = l4;
}

// ---------------- 128x128 gather-GEMM + ACT epilogue ----------------
// LDS buffer (16384 u16 = 32 KB): Ah[128][32] | Al | Bh | Bl (4096 u16 each).
// 16B slot s of row r holds k-chunk s ^ ((r>>1)&3) (bank-uniform; r6-derived).
// A rows gathered via srcmap (compacted active-token slots). Early-exit on
// padded active count. 2 blocks/CU (64 KB LDS) for inter-block overlap.
__global__ __launch_bounds__(256, 2) void gemm_act_kernel(
    const u16* __restrict__ Ahp, const u16* __restrict__ Alp,
    const u16* __restrict__ Bhp, const u16* __restrict__ Blp,
    const float* __restrict__ bias, const float* __restrict__ halt_w,
    u16* __restrict__ Hh, u16* __restrict__ Hl, float* __restrict__ zpart,
    const int* __restrict__ srcmap, const int* __restrict__ npadp, int M,
    int writeLo) {
  extern __shared__ u16 lds[];  // 2 x 16384 u16
  const int bid = blockIdx.x;                   // 1024 blocks
  const int wg = (bid & 7) * 128 + (bid >> 3);  // XCD-chunked, bijective
  const int bn0 = (wg & 7) * 128;
  const int bm0 = (wg >> 3) * 128;
  if (bm0 >= *npadp) return;  // compacted rows all below this tile
  const int t = threadIdx.x;
  const int lane = t & 63, wid = t >> 6;
  const int wr = wid >> 1, wc = wid & 1;  // wave tile 64x64
  const int g = lane >> 4, r16 = lane & 15;

  // staging: wave w stages 16-row units u0=2w, u1=2w+1 of each plane
  const int lrow = lane >> 2;                         // row within unit
  const int lchunk = (lane & 3) ^ ((lane >> 3) & 3);  // source k-chunk
  const int u0 = 2 * wid;
  int ar0 = bm0 + 16 * u0 + lrow, ar1 = ar0 + 16;
  if (srcmap) {
    ar0 = srcmap[ar0];
    ar1 = srcmap[ar1];
  }
  const int br0 = bn0 + 16 * u0 + lrow, br1 = br0 + 16;
  const u16* aSh0 = Ahp + (size_t)ar0 * D_DIM + lchunk * 8;
  const u16* aSh1 = Ahp + (size_t)ar1 * D_DIM + lchunk * 8;
  const u16* aSl0 = Alp + (size_t)ar0 * D_DIM + lchunk * 8;
  const u16* aSl1 = Alp + (size_t)ar1 * D_DIM + lchunk * 8;
  const u16* bSh0 = Bhp + (size_t)br0 * D_DIM + lchunk * 8;
  const u16* bSh1 = Bhp + (size_t)br1 * D_DIM + lchunk * 8;
  const u16* bSl0 = Blp + (size_t)br0 * D_DIM + lchunk * 8;
  const u16* bSl1 = Blp + (size_t)br1 * D_DIM + lchunk * 8;
  const int dst0 = u0 * 512 + lane * 8, dst1 = dst0 + 512;

  // fragment read offsets (u16)
  const int fsw = ((g ^ (r16 >> 1)) & 3) * 8;
  int a_rd[4], b_rd[4];
#pragma unroll
  for (int i = 0; i < 4; ++i) {
    a_rd[i] = (wr * 64 + i * 16 + r16) * 32 + fsw;
    b_rd[i] = 8192 + (wc * 64 + i * 16 + r16) * 32 + fsw;
  }

  f32x4 acc[4][4];
#pragma unroll
  for (int i = 0; i < 4; ++i)
#pragma unroll
    for (int j = 0; j < 4; ++j) acc[i][j] = (f32x4)0.0f;

  auto stage = [&](int kt) {
    const int k0 = kt << 5;
    u16* db = lds + (kt & 1) * 16384;
    glds16(aSh0 + k0, db + dst0);
    glds16(aSh1 + k0, db + dst1);
    glds16(aSl0 + k0, db + 4096 + dst0);
    glds16(aSl1 + k0, db + 4096 + dst1);
    glds16(bSh0 + k0, db + 8192 + dst0);
    glds16(bSh1 + k0, db + 8192 + dst1);
    glds16(bSl0 + k0, db + 12288 + dst0);
    glds16(bSl1 + k0, db + 12288 + dst1);
  };
  stage(0);

#pragma unroll 1
  for (int kt = 0; kt < NKT; ++kt) {
    asm volatile("s_waitcnt vmcnt(0)" ::: "memory");
    __builtin_amdgcn_s_barrier();
    asm volatile("" ::: "memory");
    const u16* Lb = lds + (kt & 1) * 16384;
    if (kt + 1 < NKT) stage(kt + 1);
    short8 ah[4], al[4], bh[4], bl[4];
#pragma unroll
    for (int i = 0; i < 4; ++i) {
      ah[i] = *(const short8*)(Lb + a_rd[i]);
      bh[i] = *(const short8*)(Lb + b_rd[i]);
    }
    __builtin_amdgcn_s_setprio(1);
#pragma unroll
    for (int i = 0; i < 4; ++i)
#pragma unroll
      for (int n = 0; n < 4; ++n) acc[i][n] = mfma16(ah[i], bh[n], acc[i][n]);
    __builtin_amdgcn_s_setprio(0);
#pragma unroll
    for (int i = 0; i < 4; ++i) {
      al[i] = *(const short8*)(Lb + 4096 + a_rd[i]);
      bl[i] = *(const short8*)(Lb + 4096 + b_rd[i]);
    }
    __builtin_amdgcn_s_setprio(1);
#pragma unroll
    for (int i = 0; i < 4; ++i)
#pragma unroll
      for (int n = 0; n < 4; ++n) acc[i][n] = mfma16(ah[i], bl[n], acc[i][n]);
#pragma unroll
    for (int i = 0; i < 4; ++i)
#pragma unroll
      for (int n = 0; n < 4; ++n) acc[i][n] = mfma16(al[i], bh[n], acc[i][n]);
    __builtin_amdgcn_s_setprio(0);
  }

  __syncthreads();  // K-loop retired; LDS free for epilogue reuse

  // ---- epilogue: bias + gelu in place, halt partial dot
  float bv[4], hwv[4];
#pragma unroll
  for (int ni = 0; ni < 4; ++ni) {
    int col = bn0 + wc * 64 + ni * 16 + r16;
    bv[ni] = bias[col];
    hwv[ni] = halt_w[col];
  }
  float zp[4][4];
#pragma unroll
  for (int mi = 0; mi < 4; ++mi)
#pragma unroll
    for (int j = 0; j < 4; ++j) {
      float zz = 0.0f;
#pragma unroll
      for (int ni = 0; ni < 4; ++ni) {
        float v = gelu_f(acc[mi][ni][j] + bv[ni]);
        acc[mi][ni][j] = v;
        zz += v * hwv[ni];
      }
      zp[mi][j] = zz;
    }
#pragma unroll
  for (int off = 1; off < 16; off <<= 1)
#pragma unroll
    for (int mi = 0; mi < 4; ++mi)
#pragma unroll
      for (int j = 0; j < 4; ++j) zp[mi][j] += __shfl_xor(zp[mi][j], off);
  float* zf = (float*)lds;  // [2][128]
  if (r16 == 0) {
#pragma unroll
    for (int mi = 0; mi < 4; ++mi)
#pragma unroll
      for (int j = 0; j < 4; ++j)
        zf[wc * 128 + wr * 64 + mi * 16 + g * 4 + j] = zp[mi][j];
  }
  __syncthreads();
  if (t < 128) zpart[(size_t)(bn0 >> 7) * M + bm0 + t] = zf[t] + zf[128 + t];
  __syncthreads();

  // ---- hi plane repack + store (hp = u16[128][128] = 32 KB)
  u16* hp = lds;
#pragma unroll
  for (int mi = 0; mi < 4; ++mi)
#pragma unroll
    for (int ni = 0; ni < 4; ++ni)
#pragma unroll
      for (int j = 0; j < 4; ++j)
        hp[(wr * 64 + mi * 16 + g * 4 + j) * 128 + wc * 64 + ni * 16 + r16] =
            f2bf(acc[mi][ni][j]);
  __syncthreads();
#pragma unroll
  for (int p = 0; p < 8; ++p) {
    int idx = p * 256 + t;
    int r = idx >> 4, c = idx & 15;
    *(short8*)(Hh + (size_t)(bm0 + r) * D_DIM + bn0 + c * 8) =
        *(const short8*)&hp[r * 128 + c * 8];
  }
  if (writeLo) {
    __syncthreads();
#pragma unroll
    for (int mi = 0; mi < 4; ++mi)
#pragma unroll
      for (int ni = 0; ni < 4; ++ni)
#pragma unroll
        for (int j = 0; j < 4; ++j) {
          float v = acc[mi][ni][j];
          hp[(wr * 64 + mi * 16 + g * 4 + j) * 128 + wc * 64 + ni * 16 + r16] =
              f2bf(v - bf2f(f2bf(v)));
        }
    __syncthreads();
#pragma unroll
    for (int p = 0; p < 8; ++p) {
      int idx = p * 256 + t;
      int r = idx >> 4, c = idx & 15;
      *(short8*)(Hl + (size_t)(bm0 + r) * D_DIM + bn0 + c * 8) =
          *(const short8*)&hp[r * 128 + c * 8];
    }
  }
}

// ---------------- ACT scalar kernels ----------------
__global__ __launch_bounds__(256) void act_weights_kernel(
    const float* __restrict__ zpart, const float* __restrict__ halt_b,
    float* __restrict__ cum, float* __restrict__ rem, float* __restrict__ pond,
    float* __restrict__ wout, const int* __restrict__ idx,
    const int* __restrict__ np, int step, int last, int M) {
  int slot = blockIdx.x * 256 + threadIdx.x;
  if (slot >= *np) return;
  int tok = idx ? idx[slot] : slot;
  float z = halt_b[0];
#pragma unroll
  for (int nb = 0; nb < 8; ++nb) z += zpart[(size_t)nb * M + slot];
  float p = 1.0f / (1.0f + expf(-z));
  float c, r, q;
  if (step == 0) {
    c = 0.0f; r = 1.0f; q = 0.0f;
  } else {
    c = cum[tok]; r = rem[tok]; q = pond[tok];
  }
  float weight = last ? r : (((c + p) >= 0.99f) ? r : p);
  q += weight;
  c += weight;
  r = fmaxf(1.0f - c, 0.0f);
  cum[tok] = c;
  rem[tok] = r;
  pond[tok] = q;
  wout[slot] = weight;
}

// deterministic single-block stream compaction of active tokens (rem > 0)
__global__ __launch_bounds__(1024) void compact_kernel(
    const float* __restrict__ rem, const int* __restrict__ idx_cur,
    const int* __restrict__ ncur_p, int* __restrict__ idx_next,
    int* __restrict__ src_next, int* __restrict__ cnt_next) {
  __shared__ int sc[1024];
  const int t = threadIdx.x;
  const int n = *ncur_p;
  const int base = t * 16;
  int lc = 0;
#pragma unroll
  for (int i = 0; i < 16; ++i) {
    int j = base + i;
    if (j < n) {
      int tok = idx_cur ? idx_cur[j] : j;
      if (rem[tok] > 0.0f) ++lc;
    }
  }
  sc[t] = lc;
  __syncthreads();
  for (int d = 1; d < 1024; d <<= 1) {
    int v = (t >= d) ? sc[t - d] : 0;
    __syncthreads();
    sc[t] += v;
    __syncthreads();
  }
  int pos = sc[t] - lc;
  const int total = sc[1023];
#pragma unroll
  for (int i = 0; i < 16; ++i) {
    int j = base + i;
    if (j < n) {
      int tok = idx_cur ? idx_cur[j] : j;
      if (rem[tok] > 0.0f) {
        idx_next[pos] = tok;
        src_next[pos] = j;
        ++pos;
      }
    }
  }
  if (t == 0) {
    int pad = (total + 127) & ~127;
    cnt_next[0] = total;
    cnt_next[1] = pad;
    for (int j = total; j < pad; ++j) {
      idx_next[j] = -1;
      src_next[j] = 0;
    }
  }
}

// out[tok] (+)= w[slot] * h[slot]   (hi plane only)
__global__ __launch_bounds__(256) void act_out_kernel(
    const u16* __restrict__ h, const float* __restrict__ w,
    const int* __restrict__ idx, const int* __restrict__ np, int accum,
    float* __restrict__ out) {
  size_t gid = (size_t)blockIdx.x * 256 + threadIdx.x;
  int slot = (int)(gid >> 7);
  if (slot >= *np) return;
  int off = ((int)gid & 127) * 8;
  int tok = idx ? idx[slot] : slot;
  size_t hb = (size_t)slot * D_DIM + off;
  size_t ob = (size_t)tok * D_DIM + off;
  float ws = w[slot];
  short8 hi = *(const short8*)(h + hb);
  float o[8];
  if (accum) {
    float4 a = *(const float4*)(out + ob);
    float4 b = *(const float4*)(out + ob + 4);
    o[0] = a.x; o[1] = a.y; o[2] = a.z; o[3] = a.w;
    o[4] = b.x; o[5] = b.y; o[6] = b.z; o[7] = b.w;
  } else {
#pragma unroll
    for (int j = 0; j < 8; ++j) o[j] = 0.0f;
  }
#pragma unroll
  for (int j = 0; j < 8; ++j) o[j] += ws * bf2f((u16)hi[j]);
  *(float4*)(out + ob) = make_float4(o[0], o[1], o[2], o[3]);
  *(float4*)(out + ob + 4) = make_float4(o[4], o[5], o[6], o[7]);
}

__global__ __launch_bounds__(256) void ponder_reduce_kernel(
    const float* __restrict__ pond, float* __restrict__ o, int n) {
  __shared__ float sh[256];
  float a = 0.0f;
  for (int i = threadIdx.x; i < n; i += 256) a += pond[i];
  sh[threadIdx.x] = a;
  __syncthreads();
  for (int s = 128; s; s >>= 1) {
    if ((int)threadIdx.x < s) sh[threadIdx.x] += sh[threadIdx.x + s];
    __syncthreads();
  }
  if (threadIdx.x == 0) o[0] = sh[0] / (float)n;
}

extern "C" void kernel_launch(void* const* d_in, const int* in_sizes, int n_in,
                              void* d_out, int out_size, void* d_ws,
                              size_t ws_size, hipStream_t stream) {
  const float* x = (const float*)d_in[0];
  const float* layer_w = (const float*)d_in[1];
  const float* layer_b = (const float*)d_in[2];
  const float* halt_w = (const float*)d_in[3];
  const float* halt_b = (const float*)d_in[4];
  float* out = (float*)d_out;

  const int D = D_DIM;
  const int M = in_sizes[0] / D;        // 16384
  const int L = in_sizes[1] / (D * D);  // 4
  const size_t MD = (size_t)M * D, DD = (size_t)D * D;

  char* ws = (char*)d_ws;
  size_t off = 0;
  auto alloc = [&](size_t bytes) {
    void* p = ws + off;
    off += (bytes + 255) & ~(size_t)255;
    return p;
  };
  u16* Wsplit = (u16*)alloc((size_t)L * 2 * DD * sizeof(u16));  // hi | lo
  float* zpart = (float*)alloc(8 * (size_t)M * 4);
  float* wbuf = (float*)alloc((size_t)M * 4);
  float* cum = (float*)alloc((size_t)M * 4);
  float* rem = (float*)alloc((size_t)M * 4);
  float* pond = (float*)alloc((size_t)M * 4);
  int* counts = (int*)alloc(16 * sizeof(int));  // [2s]=exact, [2s+1]=pad
  int* idxA = (int*)alloc((size_t)M * 4);
  int* idxB = (int*)alloc((size_t)M * 4);
  int* srcb = (int*)alloc((size_t)M * 4);

  const size_t planeElems = 2 * MD;  // hi + lo (u16)
  u16* P0 = (u16*)alloc(planeElems * 2);
  u16* P1 = (u16*)alloc(planeElems * 2);

  hipFuncSetAttribute((const void*)gemm_act_kernel,
                      hipFuncAttributeMaxDynamicSharedMemorySize, 65536);

  prep_x_kernel<<<(unsigned)(MD / 1024), 256, 0, stream>>>(x, P0, P0 + MD,
                                                           counts, M);
  prep_w_kernel<<<dim3(D / 64, D / 64, L), 256, 0, stream>>>(
      layer_w, Wsplit, Wsplit + (size_t)L * DD);

  for (int s = 0; s < L; ++s) {
    u16* pin = (s & 1) ? P1 : P0;
    u16* pout = (s & 1) ? P0 : P1;
    const int* idxs = (s == 0) ? nullptr : ((s & 1) ? idxB : idxA);
    gemm_act_kernel<<<dim3((M / 128) * (D / 128)), 256, 65536, stream>>>(
        pin, pin + MD, Wsplit + (size_t)s * DD, Wsplit + (size_t)(L + s) * DD,
        layer_b + (size_t)s * D, halt_w, pout, pout + MD, zpart,
        (s == 0) ? nullptr : srcb, counts + 2 * s + 1, M,
        (s < L - 1) ? 1 : 0);
    act_weights_kernel<<<M / 256, 256, 0, stream>>>(
        zpart, halt_b, cum, rem, pond, wbuf, idxs, counts + 2 * s, s,
        (s == L - 1) ? 1 : 0, M);
    act_out_kernel<<<(unsigned)(MD / 2048), 256, 0, stream>>>(
        pout, wbuf, idxs, counts + 2 * s, (s > 0) ? 1 : 0, out);
    if (s + 1 < L) {
      int* idxn = ((s + 1) & 1) ? idxB : idxA;
      compact_kernel<<<1, 1024, 0, stream>>>(rem, idxs, counts + 2 * s, idxn,
                                             srcb, counts + 2 * (s + 1));
    }
  }
  ponder_reduce_kernel<<<1, 256, 0, stream>>>(pond, out + MD, M);
}

// Round 12
// 495.859 us; speedup vs baseline: 1.4391x; 1.1069x over previous
//
#include <hip/hip_runtime.h>

typedef __attribute__((ext_vector_type(8))) short short8;
typedef __attribute__((ext_vector_type(4))) float f32x4;
typedef __attribute__((ext_vector_type(4))) unsigned short u16x4;
typedef unsigned short u16;

#define D_DIM 1024
#define NKT 32  // K / 32

__device__ __forceinline__ u16 f2bf(float f) {
  unsigned u = __builtin_bit_cast(unsigned, f);
  u += 0x7fffu + ((u >> 16) & 1u);
  return (u16)(u >> 16);
}
__device__ __forceinline__ float bf2f(u16 b) {
  return __builtin_bit_cast(float, ((unsigned)b) << 16);
}
__device__ __forceinline__ float gelu_f(float x) {
  float i = 0.7978845608028654f * (x + 0.044715f * x * x * x);
  float ex = __builtin_amdgcn_exp2f(i * 2.885390081777927f);  // e^{2i}
  float th = 1.0f - 2.0f * __builtin_amdgcn_rcpf(ex + 1.0f);
  return 0.5f * x * (1.0f + th);
}
__device__ __forceinline__ f32x4 mfma16(short8 a, short8 b, f32x4 c) {
  return __builtin_amdgcn_mfma_f32_16x16x32_bf16(a, b, c, 0, 0, 0);
}
__device__ __forceinline__ void glds16(const u16* g, const u16* l) {
  __builtin_amdgcn_global_load_lds(
      (const __attribute__((address_space(1))) void*)g,
      (__attribute__((address_space(3))) void*)l, 16, 0, 0);
}

// ---------------- prep kernels ----------------
__global__ __launch_bounds__(256) void prep_w_kernel(
    const float* __restrict__ W, u16* __restrict__ Wth, u16* __restrict__ Wtl) {
  __shared__ float tile[64][65];
  const int t = threadIdx.x;
  const int k0 = blockIdx.x * 64, n0 = blockIdx.y * 64;
  const size_t lbase = (size_t)blockIdx.z * D_DIM * D_DIM;
#pragma unroll
  for (int j = 0; j < 16; ++j) {
    int idx = t + 256 * j;
    int r = idx >> 6, c = idx & 63;
    tile[r][c] = W[lbase + (size_t)(k0 + r) * D_DIM + (n0 + c)];
  }
  __syncthreads();
#pragma unroll
  for (int j = 0; j < 16; ++j) {
    int idx = t + 256 * j;
    int r = idx >> 6, c = idx & 63;
    float f = tile[c][r];
    u16 hb = f2bf(f);
    u16 lb = f2bf(f - bf2f(hb));
    size_t oidx = lbase + (size_t)(n0 + r) * D_DIM + (k0 + c);
    Wth[oidx] = hb;
    Wtl[oidx] = lb;
  }
}

__global__ __launch_bounds__(256) void prep_x_kernel(
    const float* __restrict__ x, u16* __restrict__ xh, u16* __restrict__ xl,
    int* __restrict__ counts, int M) {
  if (blockIdx.x == 0 && threadIdx.x == 0) {
    counts[0] = M;  // exact count, layer 0
    counts[1] = M;  // padded count, layer 0
  }
  size_t i = ((size_t)blockIdx.x * 256 + threadIdx.x) * 4;
  const float4 v = *(const float4*)(x + i);
  const float fv[4] = {v.x, v.y, v.z, v.w};
  u16x4 h4, l4;
#pragma unroll
  for (int c = 0; c < 4; ++c) {
    u16 hb = f2bf(fv[c]);
    h4[c] = hb;
    l4[c] = f2bf(fv[c] - bf2f(hb));
  }
  *(u16x4*)(xh + i) = h4;
  *(u16x4*)(xl + i) = l4;
}

// ---------------- 128x128 gather-GEMM + ACT epilogue ----------------
// LDS buffer (16384 u16 = 32 KB): Ah[128][32] | Al | Bh | Bl (4096 u16 each).
// 16B slot s of row r holds k-chunk s ^ ((r>>1)&3) (bank-uniform).
// Block mapping (XCD = bid%8): m-tile mt = (bid&7)+8*(bid>>6) -> XCD x owns
// m-tiles == x (mod 8) (front-packed active tiles spread across all XCDs);
// all 8 bn-blocks of an m-tile stay on one XCD (A-panel read once per XCD).
// Early-exit on padded active count; 2 blocks/CU.
__global__ __launch_bounds__(256, 2) void gemm_act_kernel(
    const u16* __restrict__ Ahp, const u16* __restrict__ Alp,
    const u16* __restrict__ Bhp, const u16* __restrict__ Blp,
    const float* __restrict__ bias, const float* __restrict__ halt_w,
    u16* __restrict__ Hh, u16* __restrict__ Hl, float* __restrict__ zpart,
    const int* __restrict__ srcmap, const int* __restrict__ npadp, int M,
    int writeLo) {
  extern __shared__ u16 lds[];  // 2 x 16384 u16
  const int bid = blockIdx.x;  // 1024 blocks
  const int mt = (bid & 7) + 8 * (bid >> 6);
  const int bm0 = mt * 128;
  if (bm0 >= *npadp) return;  // compacted rows all below this tile
  const int bn0 = ((bid >> 3) & 7) * 128;
  const int t = threadIdx.x;
  const int lane = t & 63, wid = t >> 6;
  const int wr = wid >> 1, wc = wid & 1;  // wave tile 64x64
  const int g = lane >> 4, r16 = lane & 15;

  // staging: wave w stages 16-row units u0=2w, u1=2w+1 of each plane
  const int lrow = lane >> 2;                         // row within unit
  const int lchunk = (lane & 3) ^ ((lane >> 3) & 3);  // source k-chunk
  const int u0 = 2 * wid;
  int ar0 = bm0 + 16 * u0 + lrow, ar1 = ar0 + 16;
  if (srcmap) {
    ar0 = srcmap[ar0];
    ar1 = srcmap[ar1];
  }
  const int br0 = bn0 + 16 * u0 + lrow, br1 = br0 + 16;
  const u16* aSh0 = Ahp + (size_t)ar0 * D_DIM + lchunk * 8;
  const u16* aSh1 = Ahp + (size_t)ar1 * D_DIM + lchunk * 8;
  const u16* aSl0 = Alp + (size_t)ar0 * D_DIM + lchunk * 8;
  const u16* aSl1 = Alp + (size_t)ar1 * D_DIM + lchunk * 8;
  const u16* bSh0 = Bhp + (size_t)br0 * D_DIM + lchunk * 8;
  const u16* bSh1 = Bhp + (size_t)br1 * D_DIM + lchunk * 8;
  const u16* bSl0 = Blp + (size_t)br0 * D_DIM + lchunk * 8;
  const u16* bSl1 = Blp + (size_t)br1 * D_DIM + lchunk * 8;
  const int dst0 = u0 * 512 + lane * 8, dst1 = dst0 + 512;

  // fragment read offsets (u16)
  const int fsw = ((g ^ (r16 >> 1)) & 3) * 8;
  int a_rd[4], b_rd[4];
#pragma unroll
  for (int i = 0; i < 4; ++i) {
    a_rd[i] = (wr * 64 + i * 16 + r16) * 32 + fsw;
    b_rd[i] = 8192 + (wc * 64 + i * 16 + r16) * 32 + fsw;
  }

  f32x4 acc[4][4];
#pragma unroll
  for (int i = 0; i < 4; ++i)
#pragma unroll
    for (int j = 0; j < 4; ++j) acc[i][j] = (f32x4)0.0f;

  auto stage = [&](int kt) {
    const int k0 = kt << 5;
    u16* db = lds + (kt & 1) * 16384;
    glds16(aSh0 + k0, db + dst0);
    glds16(aSh1 + k0, db + dst1);
    glds16(aSl0 + k0, db + 4096 + dst0);
    glds16(aSl1 + k0, db + 4096 + dst1);
    glds16(bSh0 + k0, db + 8192 + dst0);
    glds16(bSh1 + k0, db + 8192 + dst1);
    glds16(bSl0 + k0, db + 12288 + dst0);
    glds16(bSl1 + k0, db + 12288 + dst1);
  };
  stage(0);

#pragma unroll 1
  for (int kt = 0; kt < NKT; ++kt) {
    asm volatile("s_waitcnt vmcnt(0)" ::: "memory");
    __builtin_amdgcn_s_barrier();
    asm volatile("" ::: "memory");
    const u16* Lb = lds + (kt & 1) * 16384;
    if (kt + 1 < NKT) stage(kt + 1);
    short8 ah[4], al[4], bh[4], bl[4];
#pragma unroll
    for (int i = 0; i < 4; ++i) {
      ah[i] = *(const short8*)(Lb + a_rd[i]);
      bh[i] = *(const short8*)(Lb + b_rd[i]);
    }
    __builtin_amdgcn_s_setprio(1);
#pragma unroll
    for (int i = 0; i < 4; ++i)
#pragma unroll
      for (int n = 0; n < 4; ++n) acc[i][n] = mfma16(ah[i], bh[n], acc[i][n]);
    __builtin_amdgcn_s_setprio(0);
#pragma unroll
    for (int i = 0; i < 4; ++i) {
      al[i] = *(const short8*)(Lb + 4096 + a_rd[i]);
      bl[i] = *(const short8*)(Lb + 4096 + b_rd[i]);
    }
    __builtin_amdgcn_s_setprio(1);
#pragma unroll
    for (int i = 0; i < 4; ++i)
#pragma unroll
      for (int n = 0; n < 4; ++n) acc[i][n] = mfma16(ah[i], bl[n], acc[i][n]);
#pragma unroll
    for (int i = 0; i < 4; ++i)
#pragma unroll
      for (int n = 0; n < 4; ++n) acc[i][n] = mfma16(al[i], bh[n], acc[i][n]);
    __builtin_amdgcn_s_setprio(0);
  }

  __syncthreads();  // K-loop retired; LDS free for epilogue reuse

  // ---- epilogue: bias + gelu in place, halt partial dot
  float bv[4], hwv[4];
#pragma unroll
  for (int ni = 0; ni < 4; ++ni) {
    int col = bn0 + wc * 64 + ni * 16 + r16;
    bv[ni] = bias[col];
    hwv[ni] = halt_w[col];
  }
  float zp[4][4];
#pragma unroll
  for (int mi = 0; mi < 4; ++mi)
#pragma unroll
    for (int j = 0; j < 4; ++j) {
      float zz = 0.0f;
#pragma unroll
      for (int ni = 0; ni < 4; ++ni) {
        float v = gelu_f(acc[mi][ni][j] + bv[ni]);
        acc[mi][ni][j] = v;
        zz += v * hwv[ni];
      }
      zp[mi][j] = zz;
    }
#pragma unroll
  for (int off = 1; off < 16; off <<= 1)
#pragma unroll
    for (int mi = 0; mi < 4; ++mi)
#pragma unroll
      for (int j = 0; j < 4; ++j) zp[mi][j] += __shfl_xor(zp[mi][j], off);
  float* zf = (float*)lds;  // [2][128]
  if (r16 == 0) {
#pragma unroll
    for (int mi = 0; mi < 4; ++mi)
#pragma unroll
      for (int j = 0; j < 4; ++j)
        zf[wc * 128 + wr * 64 + mi * 16 + g * 4 + j] = zp[mi][j];
  }
  __syncthreads();
  if (t < 128) zpart[(size_t)(bn0 >> 7) * M + bm0 + t] = zf[t] + zf[128 + t];
  __syncthreads();

  // ---- hi plane repack + store (hp = u16[128][128] = 32 KB)
  u16* hp = lds;
#pragma unroll
  for (int mi = 0; mi < 4; ++mi)
#pragma unroll
    for (int ni = 0; ni < 4; ++ni)
#pragma unroll
      for (int j = 0; j < 4; ++j)
        hp[(wr * 64 + mi * 16 + g * 4 + j) * 128 + wc * 64 + ni * 16 + r16] =
            f2bf(acc[mi][ni][j]);
  __syncthreads();
#pragma unroll
  for (int p = 0; p < 8; ++p) {
    int idx = p * 256 + t;
    int r = idx >> 4, c = idx & 15;
    *(short8*)(Hh + (size_t)(bm0 + r) * D_DIM + bn0 + c * 8) =
        *(const short8*)&hp[r * 128 + c * 8];
  }
  if (writeLo) {
    __syncthreads();
#pragma unroll
    for (int mi = 0; mi < 4; ++mi)
#pragma unroll
      for (int ni = 0; ni < 4; ++ni)
#pragma unroll
        for (int j = 0; j < 4; ++j) {
          float v = acc[mi][ni][j];
          hp[(wr * 64 + mi * 16 + g * 4 + j) * 128 + wc * 64 + ni * 16 + r16] =
              f2bf(v - bf2f(f2bf(v)));
        }
    __syncthreads();
#pragma unroll
    for (int p = 0; p < 8; ++p) {
      int idx = p * 256 + t;
      int r = idx >> 4, c = idx & 15;
      *(short8*)(Hl + (size_t)(bm0 + r) * D_DIM + bn0 + c * 8) =
          *(const short8*)&hp[r * 128 + c * 8];
    }
  }
}

// ---------------- ACT scalar kernels ----------------
__global__ __launch_bounds__(256) void act_weights_kernel(
    const float* __restrict__ zpart, const float* __restrict__ halt_b,
    float* __restrict__ cum, float* __restrict__ rem, float* __restrict__ pond,
    float* __restrict__ wout, const int* __restrict__ idx,
    const int* __restrict__ np, int step, int last, int M) {
  int slot = blockIdx.x * 256 + threadIdx.x;
  if (slot >= *np) return;
  int tok = idx ? idx[slot] : slot;
  float z = halt_b[0];
#pragma unroll
  for (int nb = 0; nb < 8; ++nb) z += zpart[(size_t)nb * M + slot];
  float p = 1.0f / (1.0f + expf(-z));
  float c, r, q;
  if (step == 0) {
    c = 0.0f; r = 1.0f; q = 0.0f;
  } else {
    c = cum[tok]; r = rem[tok]; q = pond[tok];
  }
  float weight = last ? r : (((c + p) >= 0.99f) ? r : p);
  q += weight;
  c += weight;
  r = fmaxf(1.0f - c, 0.0f);
  cum[tok] = c;
  rem[tok] = r;
  pond[tok] = q;
  wout[slot] = weight;
}

// deterministic single-block stream compaction of active tokens (rem > 0)
__global__ __launch_bounds__(1024) void compact_kernel(
    const float* __restrict__ rem, const int* __restrict__ idx_cur,
    const int* __restrict__ ncur_p, int* __restrict__ idx_next,
    int* __restrict__ src_next, int* __restrict__ cnt_next) {
  __shared__ int sc[1024];
  const int t = threadIdx.x;
  const int n = *ncur_p;
  const int base = t * 16;
  int lc = 0;
#pragma unroll
  for (int i = 0; i < 16; ++i) {
    int j = base + i;
    if (j < n) {
      int tok = idx_cur ? idx_cur[j] : j;
      if (rem[tok] > 0.0f) ++lc;
    }
  }
  sc[t] = lc;
  __syncthreads();
  for (int d = 1; d < 1024; d <<= 1) {
    int v = (t >= d) ? sc[t - d] : 0;
    __syncthreads();
    sc[t] += v;
    __syncthreads();
  }
  int pos = sc[t] - lc;
  const int total = sc[1023];
#pragma unroll
  for (int i = 0; i < 16; ++i) {
    int j = base + i;
    if (j < n) {
      int tok = idx_cur ? idx_cur[j] : j;
      if (rem[tok] > 0.0f) {
        idx_next[pos] = tok;
        src_next[pos] = j;
        ++pos;
      }
    }
  }
  if (t == 0) {
    int pad = (total + 127) & ~127;
    cnt_next[0] = total;
    cnt_next[1] = pad;
    for (int j = total; j < pad; ++j) {
      idx_next[j] = -1;
      src_next[j] = 0;
    }
  }
}

// out[tok] (+)= w[slot] * h[slot]   (hi plane only)
__global__ __launch_bounds__(256) void act_out_kernel(
    const u16* __restrict__ h, const float* __restrict__ w,
    const int* __restrict__ idx, const int* __restrict__ np, int accum,
    float* __restrict__ out) {
  size_t gid = (size_t)blockIdx.x * 256 + threadIdx.x;
  int slot = (int)(gid >> 7);
  if (slot >= *np) return;
  int off = ((int)gid & 127) * 8;
  int tok = idx ? idx[slot] : slot;
  size_t hb = (size_t)slot * D_DIM + off;
  size_t ob = (size_t)tok * D_DIM + off;
  float ws = w[slot];
  short8 hi = *(const short8*)(h + hb);
  float o[8];
  if (accum) {
    float4 a = *(const float4*)(out + ob);
    float4 b = *(const float4*)(out + ob + 4);
    o[0] = a.x; o[1] = a.y; o[2] = a.z; o[3] = a.w;
    o[4] = b.x; o[5] = b.y; o[6] = b.z; o[7] = b.w;
  } else {
#pragma unroll
    for (int j = 0; j < 8; ++j) o[j] = 0.0f;
  }
#pragma unroll
  for (int j = 0; j < 8; ++j) o[j] += ws * bf2f((u16)hi[j]);
  *(float4*)(out + ob) = make_float4(o[0], o[1], o[2], o[3]);
  *(float4*)(out + ob + 4) = make_float4(o[4], o[5], o[6], o[7]);
}

__global__ __launch_bounds__(256) void ponder_reduce_kernel(
    const float* __restrict__ pond, float* __restrict__ o, int n) {
  __shared__ float sh[256];
  float a = 0.0f;
  for (int i = threadIdx.x; i < n; i += 256) a += pond[i];
  sh[threadIdx.x] = a;
  __syncthreads();
  for (int s = 128; s; s >>= 1) {
    if ((int)threadIdx.x < s) sh[threadIdx.x] += sh[threadIdx.x + s];
    __syncthreads();
  }
  if (threadIdx.x == 0) o[0] = sh[0] / (float)n;
}

extern "C" void kernel_launch(void* const* d_in, const int* in_sizes, int n_in,
                              void* d_out, int out_size, void* d_ws,
                              size_t ws_size, hipStream_t stream) {
  const float* x = (const float*)d_in[0];
  const float* layer_w = (const float*)d_in[1];
  const float* layer_b = (const float*)d_in[2];
  const float* halt_w = (const float*)d_in[3];
  const float* halt_b = (const float*)d_in[4];
  float* out = (float*)d_out;

  const int D = D_DIM;
  const int M = in_sizes[0] / D;        // 16384
  const int L = in_sizes[1] / (D * D);  // 4
  const size_t MD = (size_t)M * D, DD = (size_t)D * D;

  char* ws = (char*)d_ws;
  size_t off = 0;
  auto alloc = [&](size_t bytes) {
    void* p = ws + off;
    off += (bytes + 255) & ~(size_t)255;
    return p;
  };
  u16* Wsplit = (u16*)alloc((size_t)L * 2 * DD * sizeof(u16));  // hi | lo
  float* zpart = (float*)alloc(8 * (size_t)M * 4);
  float* wbuf = (float*)alloc((size_t)M * 4);
  float* cum = (float*)alloc((size_t)M * 4);
  float* rem = (float*)alloc((size_t)M * 4);
  float* pond = (float*)alloc((size_t)M * 4);
  int* counts = (int*)alloc(16 * sizeof(int));  // [2s]=exact, [2s+1]=pad
  int* idxA = (int*)alloc((size_t)M * 4);
  int* idxB = (int*)alloc((size_t)M * 4);
  int* srcb = (int*)alloc((size_t)M * 4);

  const size_t planeElems = 2 * MD;  // hi + lo (u16)
  u16* P0 = (u16*)alloc(planeElems * 2);
  u16* P1 = (u16*)alloc(planeElems * 2);

  hipFuncSetAttribute((const void*)gemm_act_kernel,
                      hipFuncAttributeMaxDynamicSharedMemorySize, 65536);

  prep_x_kernel<<<(unsigned)(MD / 1024), 256, 0, stream>>>(x, P0, P0 + MD,
                                                           counts, M);
  prep_w_kernel<<<dim3(D / 64, D / 64, L), 256, 0, stream>>>(
      layer_w, Wsplit, Wsplit + (size_t)L * DD);

  for (int s = 0; s < L; ++s) {
    u16* pin = (s & 1) ? P1 : P0;
    u16* pout = (s & 1) ? P0 : P1;
    const int* idxs = (s == 0) ? nullptr : ((s & 1) ? idxB : idxA);
    gemm_act_kernel<<<dim3((M / 128) * (D / 128)), 256, 65536, stream>>>(
        pin, pin + MD, Wsplit + (size_t)s * DD, Wsplit + (size_t)(L + s) * DD,
        layer_b + (size_t)s * D, halt_w, pout, pout + MD, zpart,
        (s == 0) ? nullptr : srcb, counts + 2 * s + 1, M,
        (s < L - 1) ? 1 : 0);
    act_weights_kernel<<<M / 256, 256, 0, stream>>>(
        zpart, halt_b, cum, rem, pond, wbuf, idxs, counts + 2 * s, s,
        (s == L - 1) ? 1 : 0, M);
    act_out_kernel<<<(unsigned)(MD / 2048), 256, 0, stream>>>(
        pout, wbuf, idxs, counts + 2 * s, (s > 0) ? 1 : 0, out);
    if (s + 1 < L) {
      int* idxn = ((s + 1) & 1) ? idxB : idxA;
      compact_kernel<<<1, 1024, 0, stream>>>(rem, idxs, counts + 2 * s, idxn,
                                             srcb, counts + 2 * (s + 1));
    }
  }
  ponder_reduce_kernel<<<1, 256, 0, stream>>>(pond, out + MD, M);
}

// Round 13
// 461.482 us; speedup vs baseline: 1.5463x; 1.0745x over previous
//
#include <hip/hip_runtime.h>

typedef __attribute__((ext_vector_type(8))) short short8;
typedef __attribute__((ext_vector_type(4))) float f32x4;
typedef __attribute__((ext_vector_type(4))) unsigned short u16x4;
typedef unsigned short u16;

#define D_DIM 1024
#define NKT 32  // K / 32

__device__ __forceinline__ u16 f2bf(float f) {
  unsigned u = __builtin_bit_cast(unsigned, f);
  u += 0x7fffu + ((u >> 16) & 1u);
  return (u16)(u >> 16);
}
__device__ __forceinline__ float bf2f(u16 b) {
  return __builtin_bit_cast(float, ((unsigned)b) << 16);
}
__device__ __forceinline__ float gelu_f(float x) {
  float i = 0.7978845608028654f * (x + 0.044715f * x * x * x);
  float ex = __builtin_amdgcn_exp2f(i * 2.885390081777927f);  // e^{2i}
  float th = 1.0f - 2.0f * __builtin_amdgcn_rcpf(ex + 1.0f);
  return 0.5f * x * (1.0f + th);
}
__device__ __forceinline__ f32x4 mfma16(short8 a, short8 b, f32x4 c) {
  return __builtin_amdgcn_mfma_f32_16x16x32_bf16(a, b, c, 0, 0, 0);
}
__device__ __forceinline__ void glds16(const u16* g, const u16* l) {
  __builtin_amdgcn_global_load_lds(
      (const __attribute__((address_space(1))) void*)g,
      (__attribute__((address_space(3))) void*)l, 16, 0, 0);
}

// ---------------- prep kernels ----------------
__global__ __launch_bounds__(256) void prep_w_kernel(
    const float* __restrict__ W, u16* __restrict__ Wth, u16* __restrict__ Wtl) {
  __shared__ float tile[64][65];
  const int t = threadIdx.x;
  const int k0 = blockIdx.x * 64, n0 = blockIdx.y * 64;
  const size_t lbase = (size_t)blockIdx.z * D_DIM * D_DIM;
#pragma unroll
  for (int j = 0; j < 16; ++j) {
    int idx = t + 256 * j;
    int r = idx >> 6, c = idx & 63;
    tile[r][c] = W[lbase + (size_t)(k0 + r) * D_DIM + (n0 + c)];
  }
  __syncthreads();
#pragma unroll
  for (int j = 0; j < 16; ++j) {
    int idx = t + 256 * j;
    int r = idx >> 6, c = idx & 63;
    float f = tile[c][r];
    u16 hb = f2bf(f);
    u16 lb = f2bf(f - bf2f(hb));
    size_t oidx = lbase + (size_t)(n0 + r) * D_DIM + (k0 + c);
    Wth[oidx] = hb;
    Wtl[oidx] = lb;
  }
}

__global__ __launch_bounds__(256) void prep_x_kernel(
    const float* __restrict__ x, u16* __restrict__ xh, u16* __restrict__ xl,
    int* __restrict__ counts, int M) {
  if (blockIdx.x == 0 && threadIdx.x == 0) {
    counts[0] = M;  // exact count, layer 0
    counts[1] = M;  // padded count, layer 0
  }
  size_t i = ((size_t)blockIdx.x * 256 + threadIdx.x) * 4;
  const float4 v = *(const float4*)(x + i);
  const float fv[4] = {v.x, v.y, v.z, v.w};
  u16x4 h4, l4;
#pragma unroll
  for (int c = 0; c < 4; ++c) {
    u16 hb = f2bf(fv[c]);
    h4[c] = hb;
    l4[c] = f2bf(fv[c] - bf2f(hb));
  }
  *(u16x4*)(xh + i) = h4;
  *(u16x4*)(xl + i) = l4;
}

// ---------------- 128x128 gather-GEMM + ACT epilogue ----------------
// (unchanged from round 12: 32 KB dbuf, XOR bank-uniform layout, interleaved
// XCD map mt=(bid&7)+8*(bid>>6), early-exit on padded active count.)
__global__ __launch_bounds__(256, 2) void gemm_act_kernel(
    const u16* __restrict__ Ahp, const u16* __restrict__ Alp,
    const u16* __restrict__ Bhp, const u16* __restrict__ Blp,
    const float* __restrict__ bias, const float* __restrict__ halt_w,
    u16* __restrict__ Hh, u16* __restrict__ Hl, float* __restrict__ zpart,
    const int* __restrict__ srcmap, const int* __restrict__ npadp, int M,
    int writeLo) {
  extern __shared__ u16 lds[];  // 2 x 16384 u16
  const int bid = blockIdx.x;   // 1024 blocks
  const int mt = (bid & 7) + 8 * (bid >> 6);
  const int bm0 = mt * 128;
  if (bm0 >= *npadp) return;
  const int bn0 = ((bid >> 3) & 7) * 128;
  const int t = threadIdx.x;
  const int lane = t & 63, wid = t >> 6;
  const int wr = wid >> 1, wc = wid & 1;
  const int g = lane >> 4, r16 = lane & 15;

  const int lrow = lane >> 2;
  const int lchunk = (lane & 3) ^ ((lane >> 3) & 3);
  const int u0 = 2 * wid;
  int ar0 = bm0 + 16 * u0 + lrow, ar1 = ar0 + 16;
  if (srcmap) {
    ar0 = srcmap[ar0];
    ar1 = srcmap[ar1];
  }
  const int br0 = bn0 + 16 * u0 + lrow, br1 = br0 + 16;
  const u16* aSh0 = Ahp + (size_t)ar0 * D_DIM + lchunk * 8;
  const u16* aSh1 = Ahp + (size_t)ar1 * D_DIM + lchunk * 8;
  const u16* aSl0 = Alp + (size_t)ar0 * D_DIM + lchunk * 8;
  const u16* aSl1 = Alp + (size_t)ar1 * D_DIM + lchunk * 8;
  const u16* bSh0 = Bhp + (size_t)br0 * D_DIM + lchunk * 8;
  const u16* bSh1 = Bhp + (size_t)br1 * D_DIM + lchunk * 8;
  const u16* bSl0 = Blp + (size_t)br0 * D_DIM + lchunk * 8;
  const u16* bSl1 = Blp + (size_t)br1 * D_DIM + lchunk * 8;
  const int dst0 = u0 * 512 + lane * 8, dst1 = dst0 + 512;

  const int fsw = ((g ^ (r16 >> 1)) & 3) * 8;
  int a_rd[4], b_rd[4];
#pragma unroll
  for (int i = 0; i < 4; ++i) {
    a_rd[i] = (wr * 64 + i * 16 + r16) * 32 + fsw;
    b_rd[i] = 8192 + (wc * 64 + i * 16 + r16) * 32 + fsw;
  }

  f32x4 acc[4][4];
#pragma unroll
  for (int i = 0; i < 4; ++i)
#pragma unroll
    for (int j = 0; j < 4; ++j) acc[i][j] = (f32x4)0.0f;

  auto stage = [&](int kt) {
    const int k0 = kt << 5;
    u16* db = lds + (kt & 1) * 16384;
    glds16(aSh0 + k0, db + dst0);
    glds16(aSh1 + k0, db + dst1);
    glds16(aSl0 + k0, db + 4096 + dst0);
    glds16(aSl1 + k0, db + 4096 + dst1);
    glds16(bSh0 + k0, db + 8192 + dst0);
    glds16(bSh1 + k0, db + 8192 + dst1);
    glds16(bSl0 + k0, db + 12288 + dst0);
    glds16(bSl1 + k0, db + 12288 + dst1);
  };
  stage(0);

#pragma unroll 1
  for (int kt = 0; kt < NKT; ++kt) {
    asm volatile("s_waitcnt vmcnt(0)" ::: "memory");
    __builtin_amdgcn_s_barrier();
    asm volatile("" ::: "memory");
    const u16* Lb = lds + (kt & 1) * 16384;
    if (kt + 1 < NKT) stage(kt + 1);
    short8 ah[4], al[4], bh[4], bl[4];
#pragma unroll
    for (int i = 0; i < 4; ++i) {
      ah[i] = *(const short8*)(Lb + a_rd[i]);
      bh[i] = *(const short8*)(Lb + b_rd[i]);
    }
    __builtin_amdgcn_s_setprio(1);
#pragma unroll
    for (int i = 0; i < 4; ++i)
#pragma unroll
      for (int n = 0; n < 4; ++n) acc[i][n] = mfma16(ah[i], bh[n], acc[i][n]);
    __builtin_amdgcn_s_setprio(0);
#pragma unroll
    for (int i = 0; i < 4; ++i) {
      al[i] = *(const short8*)(Lb + 4096 + a_rd[i]);
      bl[i] = *(const short8*)(Lb + 4096 + b_rd[i]);
    }
    __builtin_amdgcn_s_setprio(1);
#pragma unroll
    for (int i = 0; i < 4; ++i)
#pragma unroll
      for (int n = 0; n < 4; ++n) acc[i][n] = mfma16(ah[i], bl[n], acc[i][n]);
#pragma unroll
    for (int i = 0; i < 4; ++i)
#pragma unroll
      for (int n = 0; n < 4; ++n) acc[i][n] = mfma16(al[i], bh[n], acc[i][n]);
    __builtin_amdgcn_s_setprio(0);
  }

  __syncthreads();

  float bv[4], hwv[4];
#pragma unroll
  for (int ni = 0; ni < 4; ++ni) {
    int col = bn0 + wc * 64 + ni * 16 + r16;
    bv[ni] = bias[col];
    hwv[ni] = halt_w[col];
  }
  float zp[4][4];
#pragma unroll
  for (int mi = 0; mi < 4; ++mi)
#pragma unroll
    for (int j = 0; j < 4; ++j) {
      float zz = 0.0f;
#pragma unroll
      for (int ni = 0; ni < 4; ++ni) {
        float v = gelu_f(acc[mi][ni][j] + bv[ni]);
        acc[mi][ni][j] = v;
        zz += v * hwv[ni];
      }
      zp[mi][j] = zz;
    }
#pragma unroll
  for (int off = 1; off < 16; off <<= 1)
#pragma unroll
    for (int mi = 0; mi < 4; ++mi)
#pragma unroll
      for (int j = 0; j < 4; ++j) zp[mi][j] += __shfl_xor(zp[mi][j], off);
  float* zf = (float*)lds;  // [2][128]
  if (r16 == 0) {
#pragma unroll
    for (int mi = 0; mi < 4; ++mi)
#pragma unroll
      for (int j = 0; j < 4; ++j)
        zf[wc * 128 + wr * 64 + mi * 16 + g * 4 + j] = zp[mi][j];
  }
  __syncthreads();
  if (t < 128) zpart[(size_t)(bn0 >> 7) * M + bm0 + t] = zf[t] + zf[128 + t];
  __syncthreads();

  u16* hp = lds;
#pragma unroll
  for (int mi = 0; mi < 4; ++mi)
#pragma unroll
    for (int ni = 0; ni < 4; ++ni)
#pragma unroll
      for (int j = 0; j < 4; ++j)
        hp[(wr * 64 + mi * 16 + g * 4 + j) * 128 + wc * 64 + ni * 16 + r16] =
            f2bf(acc[mi][ni][j]);
  __syncthreads();
#pragma unroll
  for (int p = 0; p < 8; ++p) {
    int idx = p * 256 + t;
    int r = idx >> 4, c = idx & 15;
    *(short8*)(Hh + (size_t)(bm0 + r) * D_DIM + bn0 + c * 8) =
        *(const short8*)&hp[r * 128 + c * 8];
  }
  if (writeLo) {
    __syncthreads();
#pragma unroll
    for (int mi = 0; mi < 4; ++mi)
#pragma unroll
      for (int ni = 0; ni < 4; ++ni)
#pragma unroll
        for (int j = 0; j < 4; ++j) {
          float v = acc[mi][ni][j];
          hp[(wr * 64 + mi * 16 + g * 4 + j) * 128 + wc * 64 + ni * 16 + r16] =
              f2bf(v - bf2f(f2bf(v)));
        }
    __syncthreads();
#pragma unroll
    for (int p = 0; p < 8; ++p) {
      int idx = p * 256 + t;
      int r = idx >> 4, c = idx & 15;
      *(short8*)(Hl + (size_t)(bm0 + r) * D_DIM + bn0 + c * 8) =
          *(const short8*)&hp[r * 128 + c * 8];
    }
  }
}

// ---------------- ACT scalar kernels ----------------
// Per-step state update. Writes per-slot weight (fallback path) AND
// token-indexed wfull/slotmap/last_step (deferred path).
__global__ __launch_bounds__(256) void act_weights_kernel(
    const float* __restrict__ zpart, const float* __restrict__ halt_b,
    float* __restrict__ cum, float* __restrict__ rem, float* __restrict__ pond,
    float* __restrict__ wout, float* __restrict__ wfull,
    int* __restrict__ slotmap, int* __restrict__ last_step,
    const int* __restrict__ idx, const int* __restrict__ np, int step,
    int last, int M) {
  int slot = blockIdx.x * 256 + threadIdx.x;
  if (slot >= *np) return;
  int tok = idx ? idx[slot] : slot;
  float z = halt_b[0];
#pragma unroll
  for (int nb = 0; nb < 8; ++nb) z += zpart[(size_t)nb * M + slot];
  float p = 1.0f / (1.0f + expf(-z));
  float c, r, q;
  if (step == 0) {
    c = 0.0f; r = 1.0f; q = 0.0f;
  } else {
    c = cum[tok]; r = rem[tok]; q = pond[tok];
  }
  float weight = last ? r : (((c + p) >= 0.99f) ? r : p);
  q += weight;
  c += weight;
  r = fmaxf(1.0f - c, 0.0f);
  cum[tok] = c;
  rem[tok] = r;
  pond[tok] = q;
  wout[slot] = weight;
  wfull[(size_t)step * M + tok] = weight;
  slotmap[(size_t)step * M + tok] = slot;
  last_step[tok] = step;
}

// deterministic single-block stream compaction of active tokens (rem > 0)
__global__ __launch_bounds__(1024) void compact_kernel(
    const float* __restrict__ rem, const int* __restrict__ idx_cur,
    const int* __restrict__ ncur_p, int* __restrict__ idx_next,
    int* __restrict__ src_next, int* __restrict__ cnt_next) {
  __shared__ int sc[1024];
  const int t = threadIdx.x;
  const int n = *ncur_p;
  const int base = t * 16;
  int lc = 0;
#pragma unroll
  for (int i = 0; i < 16; ++i) {
    int j = base + i;
    if (j < n) {
      int tok = idx_cur ? idx_cur[j] : j;
      if (rem[tok] > 0.0f) ++lc;
    }
  }
  sc[t] = lc;
  __syncthreads();
  for (int d = 1; d < 1024; d <<= 1) {
    int v = (t >= d) ? sc[t - d] : 0;
    __syncthreads();
    sc[t] += v;
    __syncthreads();
  }
  int pos = sc[t] - lc;
  const int total = sc[1023];
#pragma unroll
  for (int i = 0; i < 16; ++i) {
    int j = base + i;
    if (j < n) {
      int tok = idx_cur ? idx_cur[j] : j;
      if (rem[tok] > 0.0f) {
        idx_next[pos] = tok;
        src_next[pos] = j;
        ++pos;
      }
    }
  }
  if (t == 0) {
    int pad = (total + 127) & ~127;
    cnt_next[0] = total;
    cnt_next[1] = pad;
    for (int j = total; j < pad; ++j) {
      idx_next[j] = -1;
      src_next[j] = 0;
    }
  }
}

// Fallback per-step: out[tok] (+)= w[slot] * h[slot]   (hi plane only)
__global__ __launch_bounds__(256) void act_out_kernel(
    const u16* __restrict__ h, const float* __restrict__ w,
    const int* __restrict__ idx, const int* __restrict__ np, int accum,
    float* __restrict__ out) {
  size_t gid = (size_t)blockIdx.x * 256 + threadIdx.x;
  int slot = (int)(gid >> 7);
  if (slot >= *np) return;
  int off = ((int)gid & 127) * 8;
  int tok = idx ? idx[slot] : slot;
  size_t hb = (size_t)slot * D_DIM + off;
  size_t ob = (size_t)tok * D_DIM + off;
  float ws = w[slot];
  short8 hi = *(const short8*)(h + hb);
  float o[8];
  if (accum) {
    float4 a = *(const float4*)(out + ob);
    float4 b = *(const float4*)(out + ob + 4);
    o[0] = a.x; o[1] = a.y; o[2] = a.z; o[3] = a.w;
    o[4] = b.x; o[5] = b.y; o[6] = b.z; o[7] = b.w;
  } else {
#pragma unroll
    for (int j = 0; j < 8; ++j) o[j] = 0.0f;
  }
#pragma unroll
  for (int j = 0; j < 8; ++j) o[j] += ws * bf2f((u16)hi[j]);
  *(float4*)(out + ob) = make_float4(o[0], o[1], o[2], o[3]);
  *(float4*)(out + ob + 4) = make_float4(o[4], o[5], o[6], o[7]);
}

// Deferred: out[tok] = sum_{s<=ls} wfull[s][tok] * H_{s+1}[slotmap[s][tok]]
__global__ __launch_bounds__(256) void act_out_final_kernel(
    const u16* __restrict__ h1, const u16* __restrict__ h2,
    const u16* __restrict__ h3, const u16* __restrict__ h4,
    const float* __restrict__ wfull, const int* __restrict__ slotmap,
    const int* __restrict__ last_step, float* __restrict__ out, int M) {
  size_t gid = (size_t)blockIdx.x * 256 + threadIdx.x;
  int tok = (int)(gid >> 7);
  int off = ((int)gid & 127) * 8;
  const int ls = last_step[tok];
  float o[8];
#pragma unroll
  for (int j = 0; j < 8; ++j) o[j] = 0.0f;
  for (int s = 0; s <= ls; ++s) {
    int slot = slotmap[(size_t)s * M + tok];
    float w = wfull[(size_t)s * M + tok];
    const u16* b = (s == 0) ? h1 : (s == 1) ? h2 : (s == 2) ? h3 : h4;
    short8 hv = *(const short8*)(b + (size_t)slot * D_DIM + off);
#pragma unroll
    for (int j = 0; j < 8; ++j) o[j] += w * bf2f((u16)hv[j]);
  }
  size_t ob = (size_t)tok * D_DIM + off;
  *(float4*)(out + ob) = make_float4(o[0], o[1], o[2], o[3]);
  *(float4*)(out + ob + 4) = make_float4(o[4], o[5], o[6], o[7]);
}

__global__ __launch_bounds__(256) void ponder_reduce_kernel(
    const float* __restrict__ pond, float* __restrict__ o, int n) {
  __shared__ float sh[256];
  float a = 0.0f;
  for (int i = threadIdx.x; i < n; i += 256) a += pond[i];
  sh[threadIdx.x] = a;
  __syncthreads();
  for (int s = 128; s; s >>= 1) {
    if ((int)threadIdx.x < s) sh[threadIdx.x] += sh[threadIdx.x + s];
    __syncthreads();
  }
  if (threadIdx.x == 0) o[0] = sh[0] / (float)n;
}

extern "C" void kernel_launch(void* const* d_in, const int* in_sizes, int n_in,
                              void* d_out, int out_size, void* d_ws,
                              size_t ws_size, hipStream_t stream) {
  const float* x = (const float*)d_in[0];
  const float* layer_w = (const float*)d_in[1];
  const float* layer_b = (const float*)d_in[2];
  const float* halt_w = (const float*)d_in[3];
  const float* halt_b = (const float*)d_in[4];
  float* out = (float*)d_out;

  const int D = D_DIM;
  const int M = in_sizes[0] / D;        // 16384
  const int L = in_sizes[1] / (D * D);  // 4
  const size_t MD = (size_t)M * D, DD = (size_t)D * D;

  char* ws = (char*)d_ws;
  size_t off = 0;
  auto alloc = [&](size_t bytes) {
    void* p = ws + off;
    off += (bytes + 255) & ~(size_t)255;
    return p;
  };
  u16* Wsplit = (u16*)alloc((size_t)L * 2 * DD * sizeof(u16));  // hi | lo
  float* zpart = (float*)alloc(8 * (size_t)M * 4);
  float* wbuf = (float*)alloc((size_t)M * 4);
  float* wfull = (float*)alloc((size_t)L * M * 4);
  int* slotmap = (int*)alloc((size_t)L * M * 4);
  int* last_step = (int*)alloc((size_t)M * 4);
  float* cum = (float*)alloc((size_t)M * 4);
  float* rem = (float*)alloc((size_t)M * 4);
  float* pond = (float*)alloc((size_t)M * 4);
  int* counts = (int*)alloc(16 * sizeof(int));  // [2s]=exact, [2s+1]=pad
  int* idxA = (int*)alloc((size_t)M * 4);
  int* idxB = (int*)alloc((size_t)M * 4);
  int* srcb = (int*)alloc((size_t)M * 4);

  // planes: x pair always; deferred adds 2 archive hi planes + 2 lo planes
  // (A3/A4 overlay the dead x pair); fallback adds one full pair.
  u16* xpair = (u16*)alloc(2 * MD * sizeof(u16));  // [xh | xl]
  const bool deferred = (off + 2 * (2 * MD * sizeof(u16)) + 4096) <= ws_size;
  u16 *arch = nullptr, *lopp = nullptr, *P1 = nullptr;
  if (deferred) {
    arch = (u16*)alloc(2 * MD * sizeof(u16));  // A1 | A2
    lopp = (u16*)alloc(2 * MD * sizeof(u16));  // LB0 | LB1
  } else {
    P1 = (u16*)alloc(2 * MD * sizeof(u16));
  }
  // archive hi-plane table: A[s] holds h_s (s=1..4)
  u16* A[5] = {nullptr, arch, arch ? arch + MD : nullptr, xpair, xpair + MD};

  hipFuncSetAttribute((const void*)gemm_act_kernel,
                      hipFuncAttributeMaxDynamicSharedMemorySize, 65536);

  prep_x_kernel<<<(unsigned)(MD / 1024), 256, 0, stream>>>(x, xpair,
                                                           xpair + MD, counts,
                                                           M);
  prep_w_kernel<<<dim3(D / 64, D / 64, L), 256, 0, stream>>>(
      layer_w, Wsplit, Wsplit + (size_t)L * DD);

  for (int s = 0; s < L; ++s) {
    const int* idxs = (s == 0) ? nullptr : ((s & 1) ? idxB : idxA);
    const u16 *Ahp, *Alp;
    u16 *Hh, *Hl;
    if (deferred) {
      Ahp = (s == 0) ? xpair : A[s];
      Alp = (s == 0) ? (xpair + MD) : (lopp + (size_t)((s - 1) & 1) * MD);
      Hh = A[s + 1];
      Hl = lopp + (size_t)(s & 1) * MD;
    } else {
      u16* pin = (s & 1) ? P1 : xpair;
      u16* pout = (s & 1) ? xpair : P1;
      Ahp = pin;
      Alp = pin + MD;
      Hh = pout;
      Hl = pout + MD;
    }
    gemm_act_kernel<<<dim3((M / 128) * (D / 128)), 256, 65536, stream>>>(
        Ahp, Alp, Wsplit + (size_t)s * DD, Wsplit + (size_t)(L + s) * DD,
        layer_b + (size_t)s * D, halt_w, Hh, Hl, zpart,
        (s == 0) ? nullptr : srcb, counts + 2 * s + 1, M,
        (s < L - 1) ? 1 : 0);
    act_weights_kernel<<<M / 256, 256, 0, stream>>>(
        zpart, halt_b, cum, rem, pond, wbuf, wfull, slotmap, last_step, idxs,
        counts + 2 * s, s, (s == L - 1) ? 1 : 0, M);
    if (!deferred)
      act_out_kernel<<<(unsigned)(MD / 2048), 256, 0, stream>>>(
          Hh, wbuf, idxs, counts + 2 * s, (s > 0) ? 1 : 0, out);
    if (s + 1 < L) {
      int* idxn = ((s + 1) & 1) ? idxB : idxA;
      compact_kernel<<<1, 1024, 0, stream>>>(rem, idxs, counts + 2 * s, idxn,
                                             srcb, counts + 2 * (s + 1));
    }
  }
  if (deferred)
    act_out_final_kernel<<<(unsigned)(MD / 2048), 256, 0, stream>>>(
        A[1], A[2], A[3], A[4], wfull, slotmap, last_step, out, M);
  ponder_reduce_kernel<<<1, 256, 0, stream>>>(pond, out + MD, M);
}